// Round 1
// baseline (150.467 us; speedup 1.0000x reference)
//
#include <hip/hip_runtime.h>

// Aggregation: input [32,16,16,1024] f32 NHWC, weight [32,256,9,256] f32.
// Reference raw-reshapes the extract_patches buffer [n,16,16,9,1024] into
// [n,4,256,9,256]; flat index f = g*589824 + cw*2304 + q*256 + l decomposes
// closed-form (no divisions, since (cw&3)*2304 + q*256 + l < 9216):
//   h  = 4g + (cw>>6)
//   w  = (cw>>2) & 15
//   t2 = (cw&3)*2304 + q*256 + l ;  p = t2>>10 ; c = t2&1023
//   value = input[n, h + p/3 - 1, w + p%3 - 1, c]  (0 if out of bounds)
// out[n, g*256+cw, l] = sum_q weight[n,cw,q,l] * value
// Min traffic ~140 MB -> ~22us roofline.

__global__ __launch_bounds__(256)
void Aggregation_33320356282418_kernel(const float* __restrict__ input,
                                       const float* __restrict__ weight,
                                       float* __restrict__ out) {
    const int l   = threadIdx.x;        // 0..255  (= h'*16 + w')
    const int blk = blockIdx.x;         // n*256 + cw
    const int cw  = blk & 255;
    const int n   = blk >> 8;

    // --- load the 9 per-pixel weights into registers (reused for all 4 g) ---
    const float* wp = weight + ((size_t)(n * 256 + cw) * 9) * 256 + l;
    float wgt[9];
#pragma unroll
    for (int q = 0; q < 9; ++q) wgt[q] = wp[q * 256];

    const int hbase = cw >> 6;          // 0..3
    const int w0    = (cw >> 2) & 15;   // 0..15
    const int t2b   = (cw & 3) * 2304;

    // per-q gather params (g-independent)
    int  cq[9], diq[9], colq[9];
    bool wvalid[9];
#pragma unroll
    for (int q = 0; q < 9; ++q) {
        const int t2 = t2b + q * 256 + l;   // < 9216
        const int p  = t2 >> 10;            // 0..8
        cq[q]  = t2 & 1023;
        const int di = p / 3;               // compile-time-friendly tiny div
        const int dj = p - di * 3;
        diq[q] = di;
        const int wj = w0 + dj - 1;
        colq[q]   = wj;
        wvalid[q] = (wj >= 0) && (wj < 16);
    }

    const float* inb  = input + (size_t)n * (16 * 16 * 1024);
    float*       outb = out   + ((size_t)(n * 1024) + cw) * 256 + l;

#pragma unroll
    for (int g = 0; g < 4; ++g) {
        float acc = 0.f;
#pragma unroll
        for (int q = 0; q < 9; ++q) {
            const int hi = 4 * g + hbase + diq[q] - 1;
            float v = 0.f;
            if (wvalid[q] && (unsigned)hi < 16u) {
                v = inb[(hi * 16 + colq[q]) * 1024 + cq[q]];
            }
            acc += wgt[q] * v;
        }
        outb[(size_t)g * (256 * 256)] = acc;   // C = g*256 + cw
    }
}

extern "C" void kernel_launch(void* const* d_in, const int* in_sizes, int n_in,
                              void* d_out, int out_size, void* d_ws, size_t ws_size,
                              hipStream_t stream) {
    const float* input  = (const float*)d_in[0];   // [32,16,16,1024]
    const float* weight = (const float*)d_in[1];   // [32,256,9,256]
    float* out = (float*)d_out;                    // [32,1024,16,16]

    dim3 grid(32 * 256);   // (n, cw)
    dim3 block(256);       // l
    hipLaunchKernelGGL(Aggregation_33320356282418_kernel, grid, block, 0, stream,
                       input, weight, out);
}